// Round 5
// baseline (14.432 us; speedup 1.0000x reference)
//
#include <hip/hip_runtime.h>

// DCN cross layer, B x D f32, D = 1024, LAYERS = 3.
// x_{l+1} = x0 * (x_l . w_l) + b_l + x_l
//
// Closed form:
//   d_i = x0 . W_i;  c1 = b0.W1;  c2 = (b0+b1).W2
//   s0 = d0; s1 = (1+s0)d1 + c1; s2 = (1+s0+s1)d2 + c2
//   out = x0*(1+s0+s1+s2) + (b0+b1+b2)
//
// R5: RPW=2 (vs 4) -> 4096 waves = 4 waves/SIMD so the phased
// [load burst][L1 compute][shfl reduce][store burst] structure overlaps
// across waves and the HBM pipe stays busy. W/b still amortized 2x.

#define DDIM 1024
#define RPW 2

typedef float f32x4 __attribute__((ext_vector_type(4)));

__device__ __forceinline__ float dot4(f32x4 a, f32x4 b) {
    return fmaf(a.x, b.x, fmaf(a.y, b.y, fmaf(a.z, b.z, a.w * b.w)));
}

__global__ __launch_bounds__(256, 4) void CrossLayer_kernel(
    const float* __restrict__ x,
    const float* __restrict__ W,
    const float* __restrict__ bias,
    float* __restrict__ out,
    int B)
{
    const int wave = threadIdx.x >> 6;
    const int lane = threadIdx.x & 63;
    const int wid  = blockIdx.x * 4 + wave;
    const int row0 = wid * RPW;
    if (row0 >= B) return;

    const f32x4* w0 = reinterpret_cast<const f32x4*>(W);
    const f32x4* w1 = reinterpret_cast<const f32x4*>(W + DDIM);
    const f32x4* w2 = reinterpret_cast<const f32x4*>(W + 2 * DDIM);
    const f32x4* b0 = reinterpret_cast<const f32x4*>(bias);
    const f32x4* b1 = reinterpret_cast<const f32x4*>(bias + DDIM);
    const f32x4* b2 = reinterpret_cast<const f32x4*>(bias + 2 * DDIM);

    // ---- issue all HBM loads first (8 dwordx4 in flight per wave) ----
    f32x4 x0[RPW][4];
#pragma unroll
    for (int r = 0; r < RPW; ++r) {
        const f32x4* xr = reinterpret_cast<const f32x4*>(x + (size_t)(row0 + r) * DDIM);
#pragma unroll
        for (int c = 0; c < 4; ++c)
            x0[r][c] = xr[c * 64 + lane];
    }

    // ---- W/b pass (L1-hot), amortized over RPW rows ----
    f32x4 bsum[4];
    float d[RPW][3];
#pragma unroll
    for (int r = 0; r < RPW; ++r) { d[r][0] = d[r][1] = d[r][2] = 0.f; }
    float c1 = 0.f, c2 = 0.f;

#pragma unroll
    for (int c = 0; c < 4; ++c) {
        const int idx = c * 64 + lane;
        f32x4 wv0 = w0[idx], wv1 = w1[idx], wv2 = w2[idx];
        f32x4 bv0 = b0[idx], bv1 = b1[idx], bv2 = b2[idx];
        bsum[c] = bv0 + bv1 + bv2;
        c1 += dot4(bv0, wv1);
        f32x4 b01 = bv0 + bv1;
        c2 += dot4(b01, wv2);
#pragma unroll
        for (int r = 0; r < RPW; ++r) {
            d[r][0] += dot4(x0[r][c], wv0);
            d[r][1] += dot4(x0[r][c], wv1);
            d[r][2] += dot4(x0[r][c], wv2);
        }
    }

    // ---- one butterfly round over 8 independent values ----
#pragma unroll
    for (int off = 32; off > 0; off >>= 1) {
        c1 += __shfl_xor(c1, off, 64);
        c2 += __shfl_xor(c2, off, 64);
#pragma unroll
        for (int r = 0; r < RPW; ++r) {
            d[r][0] += __shfl_xor(d[r][0], off, 64);
            d[r][1] += __shfl_xor(d[r][1], off, 64);
            d[r][2] += __shfl_xor(d[r][2], off, 64);
        }
    }

    // ---- scalar recurrences ----
    float alpha[RPW];
#pragma unroll
    for (int r = 0; r < RPW; ++r) {
        const float t1 = 1.f + d[r][0];
        const float s1 = fmaf(t1, d[r][1], c1);
        const float t2 = t1 + s1;
        const float s2 = fmaf(t2, d[r][2], c2);
        alpha[r] = t2 + s2;
    }

    // ---- epilogue: out = x0*alpha + bsum, streaming stores ----
#pragma unroll
    for (int r = 0; r < RPW; ++r) {
        f32x4* orow = reinterpret_cast<f32x4*>(out + (size_t)(row0 + r) * DDIM);
#pragma unroll
        for (int c = 0; c < 4; ++c) {
            f32x4 o;
            o.x = fmaf(x0[r][c].x, alpha[r], bsum[c].x);
            o.y = fmaf(x0[r][c].y, alpha[r], bsum[c].y);
            o.z = fmaf(x0[r][c].z, alpha[r], bsum[c].z);
            o.w = fmaf(x0[r][c].w, alpha[r], bsum[c].w);
            __builtin_nontemporal_store(o, &orow[c * 64 + lane]);
        }
    }
}

extern "C" void kernel_launch(void* const* d_in, const int* in_sizes, int n_in,
                              void* d_out, int out_size, void* d_ws, size_t ws_size,
                              hipStream_t stream) {
    const float* x  = (const float*)d_in[0];
    const float* W  = (const float*)d_in[1];
    const float* b  = (const float*)d_in[2];
    float* out      = (float*)d_out;

    const int B = in_sizes[0] / DDIM;              // 8192
    const int rows_per_block = 4 * RPW;            // 8
    dim3 grid((B + rows_per_block - 1) / rows_per_block), block(256);
    hipLaunchKernelGGL(CrossLayer_kernel, grid, block, 0, stream,
                       x, W, b, out, B);
}